// Round 4
// baseline (1556.781 us; speedup 1.0000x reference)
//
#include <hip/hip_runtime.h>
#include <hip/hip_bf16.h>
#include <math.h>

#define BB 16
#define NN 1024
#define CC 16
#define DD 64
#define TT 32

typedef __bf16 bf16;
typedef __bf16 bf16x8 __attribute__((ext_vector_type(8)));
typedef __bf16 bf16x4 __attribute__((ext_vector_type(4)));
typedef float f32x4 __attribute__((ext_vector_type(4)));

__device__ __forceinline__ void split2(float x, bf16& h, bf16& l) {
    h = (bf16)x;
    l = (bf16)(x - (float)h);
}

// ---------------- prep: A=bf16(Mvv+I) (exact), hi/lo state inits, hi/lo weight transposes ----------------
__global__ __launch_bounds__(256) void prep_kernel(
    const float* __restrict__ Mvv, const float* __restrict__ v_init,
    const float* __restrict__ W_v, const float* __restrict__ W_vv,
    bf16* __restrict__ Abf,
    bf16* __restrict__ vhHi, bf16* __restrict__ vhLo,
    bf16* __restrict__ vhTHi, bf16* __restrict__ vhTLo,
    bf16* __restrict__ WvTh, bf16* __restrict__ WvTl,
    bf16* __restrict__ WvvTh, bf16* __restrict__ WvvTl)
{
    int gid = blockIdx.x, tid = threadIdx.x;
    if (gid < 8192) {
        size_t idx = ((size_t)gid * 256 + tid) * 8;
        const float4* p = (const float4*)(Mvv + idx);
        float4 f0 = p[0], f1 = p[1];
        int j0 = (int)(idx & (NN - 1));
        int i  = (int)((idx >> 10) & (NN - 1));
        float v[8] = {f0.x, f0.y, f0.z, f0.w, f1.x, f1.y, f1.z, f1.w};
        int di = i - j0;
        if (di >= 0 && di < 8) v[di] += 1.0f;   // self loop; values {0,1,2} exact in bf16
        bf16x8 o;
        #pragma unroll
        for (int e = 0; e < 8; ++e) o[e] = (bf16)v[e];
        *(bf16x8*)(Abf + idx) = o;
    } else if (gid < 8704) {
        size_t idx = ((size_t)(gid - 8192) * 256 + tid) * 8;   // over B*N*D
        int d0 = (int)(idx & (DD - 1));
        bf16x8 oh, ol;
        #pragma unroll
        for (int e = 0; e < 8; ++e) { bf16 h, l; split2(v_init[d0 + e], h, l); oh[e] = h; ol[e] = l; }
        *(bf16x8*)(vhHi + idx) = oh;
        *(bf16x8*)(vhLo + idx) = ol;
    } else if (gid < 9216) {
        size_t idx = ((size_t)(gid - 8704) * 256 + tid) * 8;   // over B*D*N
        int d = (int)((idx >> 10) & (DD - 1));
        bf16 h, l; split2(v_init[d], h, l);
        bf16x8 oh, ol;
        #pragma unroll
        for (int e = 0; e < 8; ++e) { oh[e] = h; ol[e] = l; }
        *(bf16x8*)(vhTHi + idx) = oh;
        *(bf16x8*)(vhTLo + idx) = ol;
    } else {
        for (int e = tid; e < DD * DD; e += 256) {
            int n = e >> 6, k = e & 63;
            bf16 h, l;
            split2(W_v[k * DD + n], h, l);   // WvT[n][k] = W_v[k][n]
            WvTh[e] = h; WvTl[e] = l;
            split2(W_vv[k * DD + n], h, l);
            WvvTh[e] = h; WvvTl[e] = l;
        }
    }
}

// ---------------- per-step kernel ----------------
__global__ __launch_bounds__(256, 1) void step_kernel(
    const bf16* __restrict__ Abf,
    const bf16* __restrict__ vhHi_in, const bf16* __restrict__ vhLo_in,
    const bf16* __restrict__ vhTHi_in, const bf16* __restrict__ vhTLo_in,
    bf16* __restrict__ vhHi_out, bf16* __restrict__ vhLo_out,
    bf16* __restrict__ vhTHi_out, bf16* __restrict__ vhTLo_out,
    const float* __restrict__ ch_in, float* __restrict__ ch_out,
    const float* __restrict__ part_prev, float* __restrict__ part_out,
    const int* __restrict__ n_colors,
    const float* __restrict__ Wc, const float* __restrict__ Wcv, const float* __restrict__ bc,
    const float* __restrict__ Wvc, const float* __restrict__ bv,
    const bf16* __restrict__ WvTh, const bf16* __restrict__ WvTl,
    const bf16* __restrict__ WvvTh, const bf16* __restrict__ WvvTl,
    int t)
{
    // Arena unioned across phases:
    //   phase 0: fp32 weight/ch staging (58,880 B)
    //   phase 1: double-buffered bf16 tiles 2 x (A 17408 + Vh 17408 + Vl 17408) = 104,448 B
    //   phase 2: sPh/sPl bf16 [64][72] x2 = 18,432 B
    __shared__ __align__(16) char arena[104448];
    __shared__ float s_vsum[64], s_mv[64], s_cs[64], s_cvec[64];

    int tid  = threadIdx.x;
    int b    = blockIdx.x >> 4;
    int blkr = blockIdx.x & 15;
    int m0   = blkr * 64;
    int ncol = n_colors[b];
    int d = tid & 63, q = tid >> 6;     // tid == q*64 + d

    // ---- phase 0: color-state update, parallel over all 256 threads ----
    {
        float* sWvc = (float*)arena;        // 4096
        float* sChI = sWvc + 4096;          // 1024
        float* sRed = sChI + 1024;          // 256
        float* sBc  = sRed + 256;           // 64
        float* sBv  = sBc  + 64;            // 64
        float* sWc  = sBv  + 64;            // 4096
        float* sWcv = sWc  + 4096;          // 4096
        float* sChN = sWcv + 4096;          // 1024

        for (int e = tid; e < 4096; e += 256) sWvc[e] = Wvc[e];
        for (int e = tid; e < 1024; e += 256) sChI[e] = ch_in[(size_t)b * 1024 + e];
        if (tid < 64) { sBc[tid] = bc[tid]; sBv[tid] = bv[tid]; }

        if (t > 0) {
            for (int e = tid; e < 4096; e += 256) { sWc[e] = Wc[e]; sWcv[e] = Wcv[e]; }
            __syncthreads();
            // vsum[d] = sum_p part_prev[b][p][d]
            {
                const float* pp = part_prev + (size_t)b * 4096;
                float s = 0.f;
                #pragma unroll
                for (int j = 0; j < 16; ++j) s += pp[(q * 16 + j) * 64 + d];
                sRed[tid] = s;
            }
            __syncthreads();
            if (tid < 64) s_vsum[tid] = sRed[tid] + sRed[tid + 64] + sRed[tid + 128] + sRed[tid + 192];
            __syncthreads();
            // mv = vsum @ W_cv
            {
                float pm = 0.f;
                #pragma unroll
                for (int j = 0; j < 16; ++j) { int k = q * 16 + j; pm += s_vsum[k] * sWcv[k * 64 + d]; }
                sRed[tid] = pm;
            }
            __syncthreads();
            if (tid < 64) s_mv[tid] = sRed[tid] + sRed[tid + 64] + sRed[tid + 128] + sRed[tid + 192];
            __syncthreads();
            // ch_t[c][d] = tanh(ch@W_c + mask*mv + bc)
            #pragma unroll
            for (int ci = 0; ci < 4; ++ci) {
                int c = q * 4 + ci;
                float s = sBc[d] + ((c < ncol) ? s_mv[d] : 0.f);
                for (int k = 0; k < 64; ++k) s += sChI[c * 64 + k] * sWc[k * 64 + d];
                float cn = tanhf(s);
                sChN[c * 64 + d] = cn;
                ch_out[(size_t)b * 1024 + c * 64 + d] = cn;  // identical across blocks of b
            }
            __syncthreads();
            // csum over active colors
            {
                float pcs = 0.f;
                #pragma unroll
                for (int ci = 0; ci < 4; ++ci) { int c = q * 4 + ci; if (c < ncol) pcs += sChN[c * 64 + d]; }
                sRed[tid] = pcs;
            }
            __syncthreads();
            if (tid < 64) s_cs[tid] = sRed[tid] + sRed[tid + 64] + sRed[tid + 128] + sRed[tid + 192];
            __syncthreads();
        } else {
            __syncthreads();
            {
                float pcs = 0.f;
                #pragma unroll
                for (int ci = 0; ci < 4; ++ci) { int c = q * 4 + ci; if (c < ncol) pcs += sChI[c * 64 + d]; }
                sRed[tid] = pcs;
            }
            __syncthreads();
            if (tid < 64) s_cs[tid] = sRed[tid] + sRed[tid + 64] + sRed[tid + 128] + sRed[tid + 192];
            __syncthreads();
        }
        // cvec = csum @ W_vc + bv
        {
            float pv = 0.f;
            #pragma unroll
            for (int j = 0; j < 16; ++j) { int k = q * 16 + j; pv += s_cs[k] * sWvc[k * 64 + d]; }
            sRed[tid] = pv;
            __syncthreads();
            if (tid < 64) s_cvec[tid] = sBv[tid] + sRed[tid] + sRed[tid + 64] + sRed[tid + 128] + sRed[tid + 192];
        }
        __syncthreads();
    }

    // ---- phase 1: v_agg = (Mvv+I) @ (vh_hi + vh_lo), double-buffered MFMA ----
    int lane = tid & 63, w = tid >> 6;
    int l16 = lane & 15, lhi = lane >> 4;

    f32x4 acc[4];
    #pragma unroll
    for (int nt = 0; nt < 4; ++nt) acc[nt] = (f32x4){0.f, 0.f, 0.f, 0.f};

    const bf16* Arow = Abf + (size_t)b * NN * NN + (size_t)m0 * NN;
    const bf16* VhG  = vhTHi_in + (size_t)b * DD * NN;
    const bf16* VlG  = vhTLo_in + (size_t)b * DD * NN;

    int r_[4], kc_[4];
    #pragma unroll
    for (int i2 = 0; i2 < 4; ++i2) { int chunk = tid + 256 * i2; r_[i2] = chunk >> 4; kc_[i2] = (chunk & 15) * 8; }

    bf16* buf0 = (bf16*)arena;
    bf16* buf1 = (bf16*)(arena + 52224);

    uint4 rA[4], rVh[4], rVl[4];
    #pragma unroll
    for (int i2 = 0; i2 < 4; ++i2) {
        size_t o = (size_t)r_[i2] * NN + kc_[i2];
        rA[i2]  = *(const uint4*)(Arow + o);
        rVh[i2] = *(const uint4*)(VhG + o);
        rVl[i2] = *(const uint4*)(VlG + o);
    }
    #pragma unroll
    for (int i2 = 0; i2 < 4; ++i2) {
        int lo = r_[i2] * 136 + kc_[i2];
        *(uint4*)(buf0 + lo) = rA[i2];
        *(uint4*)(buf0 + 8704 + lo) = rVh[i2];
        *(uint4*)(buf0 + 17408 + lo) = rVl[i2];
    }
    __syncthreads();

    for (int it = 0; it < 8; ++it) {
        if (it < 7) {
            int kt = (it + 1) * 128;
            #pragma unroll
            for (int i2 = 0; i2 < 4; ++i2) {
                size_t o = (size_t)r_[i2] * NN + kt + kc_[i2];
                rA[i2]  = *(const uint4*)(Arow + o);
                rVh[i2] = *(const uint4*)(VhG + o);
                rVl[i2] = *(const uint4*)(VlG + o);
            }
        }
        const bf16* base = (it & 1) ? buf1 : buf0;
        #pragma unroll
        for (int kk = 0; kk < 4; ++kk) {
            bf16x8 a = *(const bf16x8*)(base + (w * 16 + l16) * 136 + kk * 32 + lhi * 8);
            #pragma unroll
            for (int nt = 0; nt < 4; ++nt) {
                bf16x8 bh = *(const bf16x8*)(base + 8704  + (nt * 16 + l16) * 136 + kk * 32 + lhi * 8);
                bf16x8 bl = *(const bf16x8*)(base + 17408 + (nt * 16 + l16) * 136 + kk * 32 + lhi * 8);
                acc[nt] = __builtin_amdgcn_mfma_f32_16x16x32_bf16(a, bh, acc[nt], 0, 0, 0);
                acc[nt] = __builtin_amdgcn_mfma_f32_16x16x32_bf16(a, bl, acc[nt], 0, 0, 0);
            }
        }
        __syncthreads();
        if (it < 7) {
            bf16* bp = (it & 1) ? buf0 : buf1;
            #pragma unroll
            for (int i2 = 0; i2 < 4; ++i2) {
                int lo = r_[i2] * 136 + kc_[i2];
                *(uint4*)(bp + lo) = rA[i2];
                *(uint4*)(bp + 8704 + lo) = rVh[i2];
                *(uint4*)(bp + 17408 + lo) = rVl[i2];
            }
            __syncthreads();
        }
    }

    // ---- phase 2: pre = vh@W_v + v_agg@W_vv + cvec ; tanh ; split writes ----
    bf16* sPh = (bf16*)arena;            // [64][72]
    bf16* sPl = sPh + 64 * 72;
    #pragma unroll
    for (int nt = 0; nt < 4; ++nt)
        #pragma unroll
        for (int r = 0; r < 4; ++r) {
            bf16 h, l; split2(acc[nt][r], h, l);
            sPh[(w * 16 + lhi * 4 + r) * 72 + nt * 16 + l16] = h;
            sPl[(w * 16 + lhi * 4 + r) * 72 + nt * 16 + l16] = l;
        }
    __syncthreads();

    f32x4 acc2[4];
    #pragma unroll
    for (int nt = 0; nt < 4; ++nt) {
        float cv = s_cvec[nt * 16 + l16];
        acc2[nt] = (f32x4){cv, cv, cv, cv};
    }

    const bf16* vrh = vhHi_in + (size_t)(b * NN + m0 + w * 16 + l16) * DD;
    const bf16* vrl = vhLo_in + (size_t)(b * NN + m0 + w * 16 + l16) * DD;
    #pragma unroll
    for (int kk = 0; kk < 2; ++kk) {
        bf16x8 a1h = *(const bf16x8*)(vrh + kk * 32 + lhi * 8);
        bf16x8 a1l = *(const bf16x8*)(vrl + kk * 32 + lhi * 8);
        bf16x8 a2h = *(const bf16x8*)(sPh + (w * 16 + l16) * 72 + kk * 32 + lhi * 8);
        bf16x8 a2l = *(const bf16x8*)(sPl + (w * 16 + l16) * 72 + kk * 32 + lhi * 8);
        #pragma unroll
        for (int nt = 0; nt < 4; ++nt) {
            int woff = (nt * 16 + l16) * DD + kk * 32 + lhi * 8;
            bf16x8 b1h = *(const bf16x8*)(WvTh + woff);
            bf16x8 b1l = *(const bf16x8*)(WvTl + woff);
            bf16x8 b2h = *(const bf16x8*)(WvvTh + woff);
            bf16x8 b2l = *(const bf16x8*)(WvvTl + woff);
            acc2[nt] = __builtin_amdgcn_mfma_f32_16x16x32_bf16(a1h, b1h, acc2[nt], 0, 0, 0);
            acc2[nt] = __builtin_amdgcn_mfma_f32_16x16x32_bf16(a1l, b1h, acc2[nt], 0, 0, 0);
            acc2[nt] = __builtin_amdgcn_mfma_f32_16x16x32_bf16(a1h, b1l, acc2[nt], 0, 0, 0);
            acc2[nt] = __builtin_amdgcn_mfma_f32_16x16x32_bf16(a2h, b2h, acc2[nt], 0, 0, 0);
            acc2[nt] = __builtin_amdgcn_mfma_f32_16x16x32_bf16(a2l, b2h, acc2[nt], 0, 0, 0);
            acc2[nt] = __builtin_amdgcn_mfma_f32_16x16x32_bf16(a2h, b2l, acc2[nt], 0, 0, 0);
        }
    }

    size_t vout_base = (size_t)b * NN * DD;
    #pragma unroll
    for (int nt = 0; nt < 4; ++nt) {
        float tv[4];
        #pragma unroll
        for (int r = 0; r < 4; ++r) tv[r] = tanhf(acc2[nt][r]);
        bf16x4 pkh, pkl;
        #pragma unroll
        for (int r = 0; r < 4; ++r) {
            bf16 h, l; split2(tv[r], h, l);
            int m = m0 + w * 16 + lhi * 4 + r;
            vhHi_out[vout_base + (size_t)m * DD + nt * 16 + l16] = h;
            vhLo_out[vout_base + (size_t)m * DD + nt * 16 + l16] = l;
            pkh[r] = h; pkl[r] = l;
        }
        *(bf16x4*)(vhTHi_out + (size_t)(b * DD + nt * 16 + l16) * NN + m0 + w * 16 + lhi * 4) = pkh;
        *(bf16x4*)(vhTLo_out + (size_t)(b * DD + nt * 16 + l16) * NN + m0 + w * 16 + lhi * 4) = pkl;

        float cs = tv[0] + tv[1] + tv[2] + tv[3];
        cs += __shfl_xor(cs, 16);
        cs += __shfl_xor(cs, 32);
        if (lhi == 0)
            part_out[((size_t)b * 64 + blkr * 4 + w) * DD + nt * 16 + l16] = cs;
    }
}

// ---------------- final stage 1: per-64-node partial vote sums (256 blocks) ----------------
__global__ __launch_bounds__(256) void final_part_kernel(
    const bf16* __restrict__ vhHi, const bf16* __restrict__ vhLo,
    const float* __restrict__ W1, const float* __restrict__ b1,
    const float* __restrict__ W2, float* __restrict__ partial)
{
    __shared__ float sX[64 * 65];
    __shared__ float sW1[1024];
    __shared__ float sb1v[16], sW2v[16];
    __shared__ float sRed[256];
    int tid = threadIdx.x;
    int b = blockIdx.x >> 4, blk = blockIdx.x & 15, n0 = blk * 64;

    for (int e = tid; e < 1024; e += 256) sW1[e] = W1[e];
    if (tid < 16) { sb1v[tid] = b1[tid]; sW2v[tid] = W2[tid]; }
    {
        const bf16* gh = vhHi + ((size_t)b * NN + n0) * DD;
        const bf16* gl = vhLo + ((size_t)b * NN + n0) * DD;
        #pragma unroll
        for (int u = 0; u < 2; ++u) {
            int e = tid + u * 256;            // 512 groups of 8 bf16
            bf16x8 h8 = *(const bf16x8*)(gh + e * 8);
            bf16x8 l8 = *(const bf16x8*)(gl + e * 8);
            int row = e >> 3;
            int col = (e & 7) * 8;
            #pragma unroll
            for (int k = 0; k < 8; ++k) sX[row * 65 + col + k] = (float)h8[k] + (float)l8[k];
        }
    }
    __syncthreads();

    int nl = tid & 63, q = tid >> 6;
    float h[4];
    #pragma unroll
    for (int j = 0; j < 4; ++j) h[j] = sb1v[q * 4 + j];
    for (int dd = 0; dd < 64; ++dd) {
        float x = sX[nl * 65 + dd];
        #pragma unroll
        for (int j = 0; j < 4; ++j) h[j] += x * sW1[dd * 16 + q * 4 + j];
    }
    float pv = 0.f;
    #pragma unroll
    for (int j = 0; j < 4; ++j) pv += sW2v[q * 4 + j] / (1.f + expf(-h[j]));
    sRed[tid] = pv;
    __syncthreads();
    if (tid < 64) {
        float vote = sRed[tid] + sRed[tid + 64] + sRed[tid + 128] + sRed[tid + 192];
        #pragma unroll
        for (int off = 1; off < 64; off <<= 1) vote += __shfl_xor(vote, off);
        if (tid == 0) partial[blockIdx.x] = vote;
    }
}

// ---------------- final stage 2: reduce 16 partials per batch, mean+sigmoid ----------------
__global__ __launch_bounds__(256) void final_reduce_kernel(
    const float* __restrict__ partial, const float* __restrict__ b2, float* __restrict__ out)
{
    int tid = threadIdx.x;
    if (tid < 256) {
        int b = tid >> 4, p = tid & 15;
        float v = partial[b * 16 + p];
        #pragma unroll
        for (int off = 1; off < 16; off <<= 1) v += __shfl_xor(v, off);
        if (p == 0) out[b] = 1.f / (1.f + expf(-(v / 1024.f + b2[0])));
    }
}

extern "C" void kernel_launch(void* const* d_in, const int* in_sizes, int n_in,
                              void* d_out, int out_size, void* d_ws, size_t ws_size,
                              hipStream_t stream) {
    const float* Mvv  = (const float*)d_in[0];
    const int*   ncol = (const int*)d_in[1];
    const float* vini = (const float*)d_in[2];
    const float* ch0  = (const float*)d_in[3];
    const float* W_v  = (const float*)d_in[4];
    const float* W_vv = (const float*)d_in[5];
    const float* W_vc = (const float*)d_in[6];
    const float* b_v  = (const float*)d_in[7];
    const float* W_c  = (const float*)d_in[8];
    const float* W_cv = (const float*)d_in[9];
    const float* b_c  = (const float*)d_in[10];
    const float* W1   = (const float*)d_in[11];
    const float* b1   = (const float*)d_in[12];
    const float* W2   = (const float*)d_in[13];
    const float* b2   = (const float*)d_in[14];

    char* base = (char*)d_ws;
    size_t off = 0;
    bf16* Abf = (bf16*)(base + off); off += (size_t)BB * NN * NN * 2;       // 33,554,432
    const size_t SVH = (size_t)BB * NN * DD * 2;                             // 2,097,152
    bf16* vhHi[2]  = {(bf16*)(base + off), (bf16*)(base + off + SVH)}; off += 2 * SVH;
    bf16* vhLo[2]  = {(bf16*)(base + off), (bf16*)(base + off + SVH)}; off += 2 * SVH;
    bf16* vhTHi[2] = {(bf16*)(base + off), (bf16*)(base + off + SVH)}; off += 2 * SVH;
    bf16* vhTLo[2] = {(bf16*)(base + off), (bf16*)(base + off + SVH)}; off += 2 * SVH;
    const size_t SCH = (size_t)BB * CC * DD * 4;                             // 65,536
    float* chb[2] = {(float*)(base + off), (float*)(base + off + SCH)}; off += 2 * SCH;
    const size_t SPB = (size_t)BB * 64 * DD * 4;                             // 262,144
    float* pb[2] = {(float*)(base + off), (float*)(base + off + SPB)}; off += 2 * SPB;
    bf16* WvTh  = (bf16*)(base + off); off += DD * DD * 2;
    bf16* WvTl  = (bf16*)(base + off); off += DD * DD * 2;
    bf16* WvvTh = (bf16*)(base + off); off += DD * DD * 2;
    bf16* WvvTl = (bf16*)(base + off); off += DD * DD * 2;
    float* partial = (float*)(base + off); off += 256 * 4;

    prep_kernel<<<9217, 256, 0, stream>>>(Mvv, vini, W_v, W_vv, Abf,
        vhHi[0], vhLo[0], vhTHi[0], vhTLo[0], WvTh, WvTl, WvvTh, WvvTl);

    for (int t = 0; t < TT; ++t) {
        const float* ch_in = (t <= 1) ? ch0 : chb[(t - 1) & 1];
        int i = t & 1, o = (t + 1) & 1;
        step_kernel<<<256, 256, 0, stream>>>(Abf,
            vhHi[i], vhLo[i], vhTHi[i], vhTLo[i],
            vhHi[o], vhLo[o], vhTHi[o], vhTLo[o],
            ch_in, chb[t & 1],
            pb[(t + 1) & 1], pb[t & 1],
            ncol, W_c, W_cv, b_c, W_vc, b_v,
            WvTh, WvTl, WvvTh, WvvTl, t);
    }

    final_part_kernel<<<256, 256, 0, stream>>>(vhHi[0], vhLo[0], W1, b1, W2, partial);
    final_reduce_kernel<<<1, 256, 0, stream>>>(partial, b2, (float*)d_out);
}

// Round 5
// 1167.678 us; speedup vs baseline: 1.3332x; 1.3332x over previous
//
#include <hip/hip_runtime.h>
#include <hip/hip_bf16.h>
#include <math.h>

#define BB 16
#define NN 1024
#define CC 16
#define DD 64
#define TT 32

typedef __bf16 bf16;
typedef __bf16 bf16x8 __attribute__((ext_vector_type(8)));
typedef __bf16 bf16x4 __attribute__((ext_vector_type(4)));
typedef float f32x4 __attribute__((ext_vector_type(4)));
typedef unsigned int u32;
typedef unsigned long long u64;
typedef u32 u32v4 __attribute__((ext_vector_type(4)));

__device__ __forceinline__ void split2(float x, bf16& h, bf16& l) {
    h = (bf16)x;
    l = (bf16)(x - (float)h);
}

// Expand 8 adjacency bits (byte b8) into bf16 {0,1} values; element dr (if in [0,8))
// gets the +1 self-loop: bit? 2.0 : 1.0. All values exact in bf16.
__device__ __forceinline__ bf16x8 expand_frag(u32 b8, int dr) {
    u32 w[4];
    #pragma unroll
    for (int p = 0; p < 4; ++p) {
        u32 b0 = (b8 >> (2 * p)) & 1u;
        u32 b1 = (b8 >> (2 * p + 1)) & 1u;
        u32 lo = b0 ? 0x3F80u : 0u;
        u32 hi = b1 ? 0x3F80u : 0u;
        if (2 * p == dr)     lo = b0 ? 0x4000u : 0x3F80u;
        if (2 * p + 1 == dr) hi = b1 ? 0x4000u : 0x3F80u;
        w[p] = lo | (hi << 16);
    }
    u32v4 u = { w[0], w[1], w[2], w[3] };
    return __builtin_bit_cast(bf16x8, u);
}

// ---------------- prep: pack Mvv bits, hi/lo state inits, hi/lo weight transposes ----------------
__global__ __launch_bounds__(256) void prep_kernel(
    const float* __restrict__ Mvv, const float* __restrict__ v_init,
    const float* __restrict__ W_v, const float* __restrict__ W_vv,
    u64* __restrict__ Abits,
    bf16* __restrict__ vhHi, bf16* __restrict__ vhLo,
    bf16* __restrict__ vhTHi, bf16* __restrict__ vhTLo,
    bf16* __restrict__ WvTh, bf16* __restrict__ WvTl,
    bf16* __restrict__ WvvTh, bf16* __restrict__ WvvTl)
{
    int gid = blockIdx.x, tid = threadIdx.x;
    if (gid < 4096) {
        // pack: word W covers Mvv[b][row][wq*64 .. +64)
        int w = tid >> 6, lane = tid & 63;
        for (int it = 0; it < 16; ++it) {
            int W = gid * 64 + w * 16 + it;      // [0, 262144)
            int bb  = W >> 14;
            int row = (W >> 4) & 1023;
            int wq  = W & 15;
            float x = Mvv[(((size_t)bb << 10) + row) * 1024 + wq * 64 + lane];
            u64 m = __ballot(x != 0.0f);
            if (lane == 0) Abits[W] = m;
        }
    } else if (gid < 4608) {
        size_t idx = ((size_t)(gid - 4096) * 256 + tid) * 8;   // over B*N*D
        int d0 = (int)(idx & (DD - 1));
        bf16x8 oh, ol;
        #pragma unroll
        for (int e = 0; e < 8; ++e) { bf16 h, l; split2(v_init[d0 + e], h, l); oh[e] = h; ol[e] = l; }
        *(bf16x8*)(vhHi + idx) = oh;
        *(bf16x8*)(vhLo + idx) = ol;
    } else if (gid < 5120) {
        size_t idx = ((size_t)(gid - 4608) * 256 + tid) * 8;   // over B*D*N
        int d = (int)((idx >> 10) & (DD - 1));
        bf16 h, l; split2(v_init[d], h, l);
        bf16x8 oh, ol;
        #pragma unroll
        for (int e = 0; e < 8; ++e) { oh[e] = h; ol[e] = l; }
        *(bf16x8*)(vhTHi + idx) = oh;
        *(bf16x8*)(vhTLo + idx) = ol;
    } else {
        for (int e = tid; e < DD * DD; e += 256) {
            int n = e >> 6, k = e & 63;
            bf16 h, l;
            split2(W_v[k * DD + n], h, l);   // WvT[n][k] = W_v[k][n]
            WvTh[e] = h; WvTl[e] = l;
            split2(W_vv[k * DD + n], h, l);
            WvvTh[e] = h; WvvTl[e] = l;
        }
    }
}

// ---------------- per-step kernel ----------------
__global__ __launch_bounds__(256) void step_kernel(
    const u64* __restrict__ Abits,
    const bf16* __restrict__ vhHi_in, const bf16* __restrict__ vhLo_in,
    const bf16* __restrict__ vhTHi_in, const bf16* __restrict__ vhTLo_in,
    bf16* __restrict__ vhHi_out, bf16* __restrict__ vhLo_out,
    bf16* __restrict__ vhTHi_out, bf16* __restrict__ vhTLo_out,
    const float* __restrict__ ch_in, float* __restrict__ ch_out,
    const float* __restrict__ part_prev, float* __restrict__ part_out,
    const int* __restrict__ n_colors,
    const float* __restrict__ Wc, const float* __restrict__ Wcv, const float* __restrict__ bc,
    const float* __restrict__ Wvc, const float* __restrict__ bv,
    const bf16* __restrict__ WvTh, const bf16* __restrict__ WvTl,
    const bf16* __restrict__ WvvTh, const bf16* __restrict__ WvvTl,
    int t)
{
    // Arena: phase 0 fp32 staging (58,880 B)  ∪  phase 2 sPh/sPl (18,432 B)
    __shared__ __align__(16) char arena[59392];
    __shared__ float s_vsum[64], s_mv[64], s_cs[64], s_cvec[64];

    int tid  = threadIdx.x;
    int b    = blockIdx.x & 15;     // XCD grouping: all 16 row-blocks of batch b share L%8
    int blkr = blockIdx.x >> 4;
    int m0   = blkr * 64;
    int ncol = n_colors[b];
    int d = tid & 63, q = tid >> 6;

    // ---- phase 0: color-state update (redundant per block; deterministic fp32) ----
    {
        float* sWvc = (float*)arena;        // 4096 f
        float* sChI = sWvc + 4096;          // 1024 f
        float* sRed = sChI + 1024;          // 256 f
        float* sBc  = sRed + 256;           // 64 f
        float* sBv  = sBc  + 64;            // 64 f
        float* sWc  = sBv  + 64;            // 4096 f
        float* sWcv = sWc  + 4096;          // 4096 f
        float* sChN = sWcv + 4096;          // 1024 f

        for (int e = tid; e < 4096; e += 256) sWvc[e] = Wvc[e];
        for (int e = tid; e < 1024; e += 256) sChI[e] = ch_in[(size_t)b * 1024 + e];
        if (tid < 64) { sBc[tid] = bc[tid]; sBv[tid] = bv[tid]; }

        if (t > 0) {
            for (int e = tid; e < 4096; e += 256) { sWc[e] = Wc[e]; sWcv[e] = Wcv[e]; }
            __syncthreads();
            {   // vsum[d] over 32 partials
                const float* pp = part_prev + (size_t)b * 2048;
                float s = 0.f;
                #pragma unroll
                for (int j = 0; j < 8; ++j) s += pp[(q * 8 + j) * 64 + d];
                sRed[tid] = s;
            }
            __syncthreads();
            if (tid < 64) s_vsum[tid] = sRed[tid] + sRed[tid + 64] + sRed[tid + 128] + sRed[tid + 192];
            __syncthreads();
            {   // mv = vsum @ W_cv
                float pm = 0.f;
                #pragma unroll
                for (int j = 0; j < 16; ++j) { int k = q * 16 + j; pm += s_vsum[k] * sWcv[k * 64 + d]; }
                sRed[tid] = pm;
            }
            __syncthreads();
            if (tid < 64) s_mv[tid] = sRed[tid] + sRed[tid + 64] + sRed[tid + 128] + sRed[tid + 192];
            __syncthreads();
            #pragma unroll
            for (int ci = 0; ci < 4; ++ci) {   // ch_t[c][d]
                int c = q * 4 + ci;
                float s = sBc[d] + ((c < ncol) ? s_mv[d] : 0.f);
                for (int k = 0; k < 64; ++k) s += sChI[c * 64 + k] * sWc[k * 64 + d];
                float cn = tanhf(s);
                sChN[c * 64 + d] = cn;
                ch_out[(size_t)b * 1024 + c * 64 + d] = cn;
            }
            __syncthreads();
            {
                float pcs = 0.f;
                #pragma unroll
                for (int ci = 0; ci < 4; ++ci) { int c = q * 4 + ci; if (c < ncol) pcs += sChN[c * 64 + d]; }
                sRed[tid] = pcs;
            }
            __syncthreads();
            if (tid < 64) s_cs[tid] = sRed[tid] + sRed[tid + 64] + sRed[tid + 128] + sRed[tid + 192];
            __syncthreads();
        } else {
            __syncthreads();
            {
                float pcs = 0.f;
                #pragma unroll
                for (int ci = 0; ci < 4; ++ci) { int c = q * 4 + ci; if (c < ncol) pcs += sChI[c * 64 + d]; }
                sRed[tid] = pcs;
            }
            __syncthreads();
            if (tid < 64) s_cs[tid] = sRed[tid] + sRed[tid + 64] + sRed[tid + 128] + sRed[tid + 192];
            __syncthreads();
        }
        {   // cvec = csum @ W_vc + bv
            float pv = 0.f;
            #pragma unroll
            for (int j = 0; j < 16; ++j) { int k = q * 16 + j; pv += s_cs[k] * sWvc[k * 64 + d]; }
            sRed[tid] = pv;
            __syncthreads();
            if (tid < 64) s_cvec[tid] = sBv[tid] + sRed[tid] + sRed[tid + 64] + sRed[tid + 128] + sRed[tid + 192];
        }
        __syncthreads();
    }

    // ---- phase 1: v_agg = (Mvv+I) @ (vh_hi + vh_lo). No LDS, no barriers. ----
    int lane = tid & 63, w = tid >> 6;
    int l16 = lane & 15, lhi = lane >> 4;
    int wm = w >> 1, wn = w & 1;            // 2M x 2N wave grid; wave owns 32x32 output

    f32x4 acc[2][2];
    #pragma unroll
    for (int mi = 0; mi < 2; ++mi)
        #pragma unroll
        for (int nt = 0; nt < 2; ++nt) acc[mi][nt] = (f32x4){0.f, 0.f, 0.f, 0.f};

    const u64* Arow0 = Abits + ((size_t)b * NN + m0) * 16;
    const bf16* Vh = vhTHi_in + (size_t)b * DD * NN;
    const bf16* Vl = vhTLo_in + (size_t)b * DD * NN;

    int row0  = wm * 32 + l16;              // + mi*16
    for (int kt = 0; kt < NN; kt += 128) {
        u32v4 aw[2];
        #pragma unroll
        for (int mi = 0; mi < 2; ++mi)
            aw[mi] = *(const u32v4*)(Arow0 + (size_t)(row0 + mi * 16) * 16 + (kt >> 6));
        #pragma unroll
        for (int kk = 0; kk < 4; ++kk) {
            int col0 = kt + kk * 32 + lhi * 8;
            bf16x8 afr[2];
            #pragma unroll
            for (int mi = 0; mi < 2; ++mi) {
                u32 b8 = (aw[mi][kk] >> (lhi * 8)) & 0xFFu;
                afr[mi] = expand_frag(b8, m0 + row0 + mi * 16 - col0);
            }
            #pragma unroll
            for (int nt = 0; nt < 2; ++nt) {
                size_t bo = (size_t)(wn * 32 + nt * 16 + l16) * NN + col0;
                bf16x8 bh = *(const bf16x8*)(Vh + bo);
                bf16x8 bl = *(const bf16x8*)(Vl + bo);
                #pragma unroll
                for (int mi = 0; mi < 2; ++mi) {
                    acc[mi][nt] = __builtin_amdgcn_mfma_f32_16x16x32_bf16(afr[mi], bh, acc[mi][nt], 0, 0, 0);
                    acc[mi][nt] = __builtin_amdgcn_mfma_f32_16x16x32_bf16(afr[mi], bl, acc[mi][nt], 0, 0, 0);
                }
            }
        }
    }

    // ---- phase 2: pre = vh@W_v + v_agg@W_vv + cvec ; tanh ; split writes ----
    bf16* sPh = (bf16*)arena;            // [64][72]
    bf16* sPl = sPh + 64 * 72;
    #pragma unroll
    for (int mi = 0; mi < 2; ++mi)
        #pragma unroll
        for (int nt = 0; nt < 2; ++nt)
            #pragma unroll
            for (int r = 0; r < 4; ++r) {
                bf16 h, l; split2(acc[mi][nt][r], h, l);
                int row = wm * 32 + mi * 16 + lhi * 4 + r;
                int col = wn * 32 + nt * 16 + l16;
                sPh[row * 72 + col] = h;
                sPl[row * 72 + col] = l;
            }
    __syncthreads();

    f32x4 acc2[2][2];
    #pragma unroll
    for (int mi = 0; mi < 2; ++mi)
        #pragma unroll
        for (int nt = 0; nt < 2; ++nt) {
            float cv = s_cvec[wn * 32 + nt * 16 + l16];
            acc2[mi][nt] = (f32x4){cv, cv, cv, cv};
        }

    #pragma unroll
    for (int kk = 0; kk < 2; ++kk) {
        int ko = kk * 32 + lhi * 8;
        bf16x8 a1h[2], a1l[2], a2h[2], a2l[2];
        #pragma unroll
        for (int mi = 0; mi < 2; ++mi) {
            size_t vo = (size_t)(b * NN + m0 + wm * 32 + mi * 16 + l16) * DD + ko;
            a1h[mi] = *(const bf16x8*)(vhHi_in + vo);
            a1l[mi] = *(const bf16x8*)(vhLo_in + vo);
            int po = (wm * 32 + mi * 16 + l16) * 72 + ko;
            a2h[mi] = *(const bf16x8*)(sPh + po);
            a2l[mi] = *(const bf16x8*)(sPl + po);
        }
        #pragma unroll
        for (int nt = 0; nt < 2; ++nt) {
            int woff = (wn * 32 + nt * 16 + l16) * DD + ko;
            bf16x8 b1h = *(const bf16x8*)(WvTh + woff);
            bf16x8 b1l = *(const bf16x8*)(WvTl + woff);
            bf16x8 b2h = *(const bf16x8*)(WvvTh + woff);
            bf16x8 b2l = *(const bf16x8*)(WvvTl + woff);
            #pragma unroll
            for (int mi = 0; mi < 2; ++mi) {
                acc2[mi][nt] = __builtin_amdgcn_mfma_f32_16x16x32_bf16(a1h[mi], b1h, acc2[mi][nt], 0, 0, 0);
                acc2[mi][nt] = __builtin_amdgcn_mfma_f32_16x16x32_bf16(a1l[mi], b1h, acc2[mi][nt], 0, 0, 0);
                acc2[mi][nt] = __builtin_amdgcn_mfma_f32_16x16x32_bf16(a1h[mi], b1l, acc2[mi][nt], 0, 0, 0);
                acc2[mi][nt] = __builtin_amdgcn_mfma_f32_16x16x32_bf16(a2h[mi], b2h, acc2[mi][nt], 0, 0, 0);
                acc2[mi][nt] = __builtin_amdgcn_mfma_f32_16x16x32_bf16(a2l[mi], b2h, acc2[mi][nt], 0, 0, 0);
                acc2[mi][nt] = __builtin_amdgcn_mfma_f32_16x16x32_bf16(a2h[mi], b2l, acc2[mi][nt], 0, 0, 0);
            }
        }
    }

    size_t vout_base = (size_t)b * NN * DD;
    float csum[2] = {0.f, 0.f};
    #pragma unroll
    for (int mi = 0; mi < 2; ++mi)
        #pragma unroll
        for (int nt = 0; nt < 2; ++nt) {
            float tv[4];
            #pragma unroll
            for (int r = 0; r < 4; ++r) tv[r] = tanhf(acc2[mi][nt][r]);
            int col = wn * 32 + nt * 16 + l16;
            bf16x4 pkh, pkl;
            #pragma unroll
            for (int r = 0; r < 4; ++r) {
                bf16 h, l; split2(tv[r], h, l);
                int m = m0 + wm * 32 + mi * 16 + lhi * 4 + r;
                vhHi_out[vout_base + (size_t)m * DD + col] = h;
                vhLo_out[vout_base + (size_t)m * DD + col] = l;
                pkh[r] = h; pkl[r] = l;
            }
            size_t to = (size_t)(b * DD + col) * NN + m0 + wm * 32 + mi * 16 + lhi * 4;
            *(bf16x4*)(vhTHi_out + to) = pkh;
            *(bf16x4*)(vhTLo_out + to) = pkl;
            csum[nt] += tv[0] + tv[1] + tv[2] + tv[3];
        }
    #pragma unroll
    for (int nt = 0; nt < 2; ++nt) {
        float cs = csum[nt];
        cs += __shfl_xor(cs, 16);
        cs += __shfl_xor(cs, 32);
        if (lhi == 0)
            part_out[(((size_t)b * 16 + blkr) * 2 + wm) * 64 + wn * 32 + nt * 16 + l16] = cs;
    }
}

// ---------------- final stage 1: per-64-node partial vote sums (256 blocks) ----------------
__global__ __launch_bounds__(256) void final_part_kernel(
    const bf16* __restrict__ vhHi, const bf16* __restrict__ vhLo,
    const float* __restrict__ W1, const float* __restrict__ b1,
    const float* __restrict__ W2, float* __restrict__ partial)
{
    __shared__ float sX[64 * 65];
    __shared__ float sW1[1024];
    __shared__ float sb1v[16], sW2v[16];
    __shared__ float sRed[256];
    int tid = threadIdx.x;
    int b = blockIdx.x & 15, blk = blockIdx.x >> 4, n0 = blk * 64;

    for (int e = tid; e < 1024; e += 256) sW1[e] = W1[e];
    if (tid < 16) { sb1v[tid] = b1[tid]; sW2v[tid] = W2[tid]; }
    {
        const bf16* gh = vhHi + ((size_t)b * NN + n0) * DD;
        const bf16* gl = vhLo + ((size_t)b * NN + n0) * DD;
        #pragma unroll
        for (int u = 0; u < 2; ++u) {
            int e = tid + u * 256;
            bf16x8 h8 = *(const bf16x8*)(gh + e * 8);
            bf16x8 l8 = *(const bf16x8*)(gl + e * 8);
            int row = e >> 3;
            int col = (e & 7) * 8;
            #pragma unroll
            for (int k = 0; k < 8; ++k) sX[row * 65 + col + k] = (float)h8[k] + (float)l8[k];
        }
    }
    __syncthreads();

    int nl = tid & 63, q = tid >> 6;
    float h[4];
    #pragma unroll
    for (int j = 0; j < 4; ++j) h[j] = sb1v[q * 4 + j];
    for (int dd = 0; dd < 64; ++dd) {
        float x = sX[nl * 65 + dd];
        #pragma unroll
        for (int j = 0; j < 4; ++j) h[j] += x * sW1[dd * 16 + q * 4 + j];
    }
    float pv = 0.f;
    #pragma unroll
    for (int j = 0; j < 4; ++j) pv += sW2v[q * 4 + j] / (1.f + expf(-h[j]));
    sRed[tid] = pv;
    __syncthreads();
    if (tid < 64) {
        float vote = sRed[tid] + sRed[tid + 64] + sRed[tid + 128] + sRed[tid + 192];
        #pragma unroll
        for (int off = 1; off < 64; off <<= 1) vote += __shfl_xor(vote, off);
        if (tid == 0) partial[blockIdx.x] = vote;
    }
}

// ---------------- final stage 2 ----------------
__global__ __launch_bounds__(256) void final_reduce_kernel(
    const float* __restrict__ partial, const float* __restrict__ b2, float* __restrict__ out)
{
    int tid = threadIdx.x;
    int b = tid >> 4, p = tid & 15;
    float v = partial[p * 16 + b];
    #pragma unroll
    for (int off = 1; off < 16; off <<= 1) v += __shfl_xor(v, off);
    if (p == 0) out[b] = 1.f / (1.f + expf(-(v / 1024.f + b2[0])));
}

extern "C" void kernel_launch(void* const* d_in, const int* in_sizes, int n_in,
                              void* d_out, int out_size, void* d_ws, size_t ws_size,
                              hipStream_t stream) {
    const float* Mvv  = (const float*)d_in[0];
    const int*   ncol = (const int*)d_in[1];
    const float* vini = (const float*)d_in[2];
    const float* ch0  = (const float*)d_in[3];
    const float* W_v  = (const float*)d_in[4];
    const float* W_vv = (const float*)d_in[5];
    const float* W_vc = (const float*)d_in[6];
    const float* b_v  = (const float*)d_in[7];
    const float* W_c  = (const float*)d_in[8];
    const float* W_cv = (const float*)d_in[9];
    const float* b_c  = (const float*)d_in[10];
    const float* W1   = (const float*)d_in[11];
    const float* b1   = (const float*)d_in[12];
    const float* W2   = (const float*)d_in[13];
    const float* b2   = (const float*)d_in[14];

    char* base = (char*)d_ws;
    size_t off = 0;
    u64* Abits = (u64*)(base + off); off += (size_t)BB * NN * 16 * 8;        // 2,097,152
    const size_t SVH = (size_t)BB * NN * DD * 2;                              // 2,097,152
    bf16* vhHi[2]  = {(bf16*)(base + off), (bf16*)(base + off + SVH)}; off += 2 * SVH;
    bf16* vhLo[2]  = {(bf16*)(base + off), (bf16*)(base + off + SVH)}; off += 2 * SVH;
    bf16* vhTHi[2] = {(bf16*)(base + off), (bf16*)(base + off + SVH)}; off += 2 * SVH;
    bf16* vhTLo[2] = {(bf16*)(base + off), (bf16*)(base + off + SVH)}; off += 2 * SVH;
    const size_t SCH = (size_t)BB * CC * DD * 4;                              // 65,536
    float* chb[2] = {(float*)(base + off), (float*)(base + off + SCH)}; off += 2 * SCH;
    const size_t SPB = (size_t)BB * 32 * DD * 4;                              // 131,072
    float* pb[2] = {(float*)(base + off), (float*)(base + off + SPB)}; off += 2 * SPB;
    bf16* WvTh  = (bf16*)(base + off); off += DD * DD * 2;
    bf16* WvTl  = (bf16*)(base + off); off += DD * DD * 2;
    bf16* WvvTh = (bf16*)(base + off); off += DD * DD * 2;
    bf16* WvvTl = (bf16*)(base + off); off += DD * DD * 2;
    float* partial = (float*)(base + off); off += 256 * 4;

    prep_kernel<<<5121, 256, 0, stream>>>(Mvv, vini, W_v, W_vv, Abits,
        vhHi[0], vhLo[0], vhTHi[0], vhTLo[0], WvTh, WvTl, WvvTh, WvvTl);

    for (int t = 0; t < TT; ++t) {
        const float* ch_in = (t <= 1) ? ch0 : chb[(t - 1) & 1];
        int i = t & 1, o = (t + 1) & 1;
        step_kernel<<<256, 256, 0, stream>>>(Abits,
            vhHi[i], vhLo[i], vhTHi[i], vhTLo[i],
            vhHi[o], vhLo[o], vhTHi[o], vhTLo[o],
            ch_in, chb[t & 1],
            pb[(t + 1) & 1], pb[t & 1],
            ncol, W_c, W_cv, b_c, W_vc, b_v,
            WvTh, WvTl, WvvTh, WvvTl, t);
    }

    final_part_kernel<<<256, 256, 0, stream>>>(vhHi[0], vhLo[0], W1, b1, W2, partial);
    final_reduce_kernel<<<1, 256, 0, stream>>>(partial, b2, (float*)d_out);
}

// Round 7
// 740.283 us; speedup vs baseline: 2.1030x; 1.5773x over previous
//
#include <hip/hip_runtime.h>
#include <hip/hip_bf16.h>
#include <math.h>

#define BB 16
#define NN 1024
#define CC 16
#define DD 64
#define TT 32

typedef __bf16 bf16;
typedef __bf16 bf16x8 __attribute__((ext_vector_type(8)));
typedef __bf16 bf16x4 __attribute__((ext_vector_type(4)));
typedef float f32x4 __attribute__((ext_vector_type(4)));
typedef unsigned int u32;
typedef unsigned long long u64;
typedef u32 u32v4 __attribute__((ext_vector_type(4)));

__device__ __forceinline__ void split2(float x, bf16& h, bf16& l) {
    h = (bf16)x;
    l = (bf16)(x - (float)h);
}

// Pure bit expansion: 8 bits -> bf16 {0.0, 1.0} x8. Self-loop handled in phase 2.
__device__ __forceinline__ bf16x8 expand_bits(u32 b8) {
    u32 w[4];
    #pragma unroll
    for (int p = 0; p < 4; ++p) {
        u32 tt = b8 >> (2 * p);
        w[p] = ((tt & 1u) | ((tt & 2u) << 15)) * 0x3F80u;
    }
    u32v4 u = { w[0], w[1], w[2], w[3] };
    return __builtin_bit_cast(bf16x8, u);
}

// Vfrag layout: [b][ks=node>>5][j=d][khi=(node>>3)&3][e=node&7], bf16.

// ---------------- prep ----------------
__global__ __launch_bounds__(256) void prep_kernel(
    const float* __restrict__ Mvv, const float* __restrict__ v_init,
    const float* __restrict__ W_v, const float* __restrict__ W_vv,
    u64* __restrict__ Abits,
    bf16* __restrict__ vhHi, bf16* __restrict__ vhLo,
    bf16* __restrict__ VfHi, bf16* __restrict__ VfLo,
    bf16* __restrict__ WvTh, bf16* __restrict__ WvTl,
    bf16* __restrict__ WvvTh, bf16* __restrict__ WvvTl)
{
    int gid = blockIdx.x, tid = threadIdx.x;
    if (gid < 4096) {
        int w = tid >> 6, lane = tid & 63;
        for (int it = 0; it < 16; ++it) {
            int W = gid * 64 + w * 16 + it;      // [0, 262144)
            int bb  = W >> 14;
            int row = (W >> 4) & 1023;
            int wq  = W & 15;
            float x = Mvv[(((size_t)bb << 10) + row) * 1024 + wq * 64 + lane];
            u64 m = __ballot(x != 0.0f);
            if (lane == 0) Abits[W] = m;
        }
    } else if (gid < 4608) {
        size_t idx = ((size_t)(gid - 4096) * 256 + tid) * 8;   // over B*N*D (row-major vh)
        int d0 = (int)(idx & (DD - 1));
        bf16x8 oh, ol;
        #pragma unroll
        for (int e = 0; e < 8; ++e) { bf16 h, l; split2(v_init[d0 + e], h, l); oh[e] = h; ol[e] = l; }
        *(bf16x8*)(vhHi + idx) = oh;
        *(bf16x8*)(vhLo + idx) = ol;
    } else if (gid < 5120) {
        size_t idx = ((size_t)(gid - 4608) * 256 + tid) * 8;   // over Vfrag flat (B*64K)
        int j = (int)((idx >> 5) & 63);
        bf16 h, l; split2(v_init[j], h, l);
        bf16x8 oh, ol;
        #pragma unroll
        for (int e = 0; e < 8; ++e) { oh[e] = h; ol[e] = l; }
        *(bf16x8*)(VfHi + idx) = oh;
        *(bf16x8*)(VfLo + idx) = ol;
    } else {
        for (int e = tid; e < DD * DD; e += 256) {
            int n = e >> 6, k = e & 63;
            bf16 h, l;
            split2(W_v[k * DD + n], h, l);   // WvT[n][k] = W_v[k][n]
            WvTh[e] = h; WvTl[e] = l;
            split2(W_vv[k * DD + n], h, l);
            WvvTh[e] = h; WvvTl[e] = l;
        }
    }
}

// ---------------- per-step kernel: 512 threads (8 waves), 64 rows per block ----------------
__global__ __launch_bounds__(512, 2) void step_kernel(
    const u64* __restrict__ Abits,
    const bf16* __restrict__ vhHi_in, const bf16* __restrict__ vhLo_in,
    const bf16* __restrict__ VfHi_in, const bf16* __restrict__ VfLo_in,
    bf16* __restrict__ vhHi_out, bf16* __restrict__ vhLo_out,
    bf16* __restrict__ VfHi_out, bf16* __restrict__ VfLo_out,
    const float* __restrict__ ch_in, float* __restrict__ ch_out,
    const float* __restrict__ part_prev, float* __restrict__ part_out,
    const int* __restrict__ n_colors,
    const float* __restrict__ Wc, const float* __restrict__ Wcv, const float* __restrict__ bc,
    const float* __restrict__ Wvc, const float* __restrict__ bv,
    const bf16* __restrict__ WvTh, const bf16* __restrict__ WvTl,
    const bf16* __restrict__ WvvTh, const bf16* __restrict__ WvvTl,
    int t)
{
    __shared__ float sWc[4096], sWcv[4096], sWvc[4096];
    __shared__ float sChI[1024], sChN[1024], sPart[4096];
    __shared__ float sRed[512];
    __shared__ float sBc[64], sBv[64], sVs[64], sMv[64], sCs[64], sCv[64];
    __shared__ float vagg[2][64 * 65];

    int tid  = threadIdx.x;
    int b    = blockIdx.x & 15;     // all 16 row-blocks of batch b on same XCD
    int blkr = blockIdx.x >> 4;
    int m0   = blkr * 64;
    int ncol = n_colors[b];
    int d = tid & 63, q = tid >> 6;

    // ---- staging (issued early; latency hides under phase 1) ----
    for (int e = tid; e < 4096; e += 512) { sWvc[e] = Wvc[e]; sWc[e] = Wc[e]; sWcv[e] = Wcv[e]; }
    for (int e = tid; e < 1024; e += 512) sChI[e] = ch_in[(size_t)b * 1024 + e];
    if (t > 0)
        for (int e = tid; e < 4096; e += 512) sPart[e] = part_prev[(size_t)b * 4096 + e];
    if (tid < 64) { sBc[tid] = bc[tid]; sBv[tid] = bv[tid]; }

    // ---- phase 1: v_agg(partial) = Mvv_bits @ (vh_hi + vh_lo); regs/global only ----
    int lane = tid & 63, w = tid >> 6;
    int l16 = lane & 15, lhi = lane >> 4;
    int wm = w & 1, wn = (w >> 1) & 1, wk = w >> 2;

    f32x4 acc[2][2];
    #pragma unroll
    for (int mi = 0; mi < 2; ++mi)
        #pragma unroll
        for (int nt = 0; nt < 2; ++nt) acc[mi][nt] = (f32x4){0.f, 0.f, 0.f, 0.f};

    const u64* Ab = Abits + ((size_t)b * NN + m0 + wm * 32 + l16) * 16 + wk * 8;
    const bf16* VfH = VfHi_in + (size_t)b * 65536;
    const bf16* VfL = VfLo_in + (size_t)b * 65536;

    #pragma unroll
    for (int kt = 0; kt < 4; ++kt) {
        u32v4 aw0 = *(const u32v4*)(Ab + kt * 2);
        u32v4 aw1 = *(const u32v4*)(Ab + 256 + kt * 2);    // mi=1: +16 rows * 16 words
        #pragma unroll
        for (int kk = 0; kk < 4; ++kk) {
            int ks = wk * 16 + kt * 4 + kk;
            bf16x8 a0 = expand_bits((aw0[kk] >> (lhi * 8)) & 0xFFu);
            bf16x8 a1 = expand_bits((aw1[kk] >> (lhi * 8)) & 0xFFu);
            size_t fo = (size_t)ks * 2048 + (wn * 32 + l16) * 32 + lhi * 8;
            bf16x8 bh0 = *(const bf16x8*)(VfH + fo);
            bf16x8 bl0 = *(const bf16x8*)(VfL + fo);
            bf16x8 bh1 = *(const bf16x8*)(VfH + fo + 512); // nt=1: +16 j * 32
            bf16x8 bl1 = *(const bf16x8*)(VfL + fo + 512);
            acc[0][0] = __builtin_amdgcn_mfma_f32_16x16x32_bf16(a0, bh0, acc[0][0], 0, 0, 0);
            acc[0][1] = __builtin_amdgcn_mfma_f32_16x16x32_bf16(a0, bh1, acc[0][1], 0, 0, 0);
            acc[1][0] = __builtin_amdgcn_mfma_f32_16x16x32_bf16(a1, bh0, acc[1][0], 0, 0, 0);
            acc[1][1] = __builtin_amdgcn_mfma_f32_16x16x32_bf16(a1, bh1, acc[1][1], 0, 0, 0);
            acc[0][0] = __builtin_amdgcn_mfma_f32_16x16x32_bf16(a0, bl0, acc[0][0], 0, 0, 0);
            acc[0][1] = __builtin_amdgcn_mfma_f32_16x16x32_bf16(a0, bl1, acc[0][1], 0, 0, 0);
            acc[1][0] = __builtin_amdgcn_mfma_f32_16x16x32_bf16(a1, bl0, acc[1][0], 0, 0, 0);
            acc[1][1] = __builtin_amdgcn_mfma_f32_16x16x32_bf16(a1, bl1, acc[1][1], 0, 0, 0);
        }
    }

    // partial acc -> LDS (per K-half)
    #pragma unroll
    for (int mi = 0; mi < 2; ++mi)
        #pragma unroll
        for (int nt = 0; nt < 2; ++nt)
            #pragma unroll
            for (int r = 0; r < 4; ++r)
                vagg[wk][(wm * 32 + mi * 16 + lhi * 4 + r) * 65 + wn * 32 + nt * 16 + l16] = acc[mi][nt][r];

    __syncthreads();

    // ---- phase 0: color-state update (all 512 threads) ----
    if (t > 0) {
        {
            float s = 0.f;
            #pragma unroll
            for (int j = 0; j < 8; ++j) s += sPart[(q * 8 + j) * 64 + d];
            sRed[tid] = s;
        }
        __syncthreads();
        if (tid < 64) {
            float v = 0.f;
            #pragma unroll
            for (int i = 0; i < 8; ++i) v += sRed[tid + 64 * i];
            sVs[tid] = v;
        }
        __syncthreads();
        {
            float pm = 0.f;
            #pragma unroll
            for (int j = 0; j < 8; ++j) { int k = q * 8 + j; pm += sVs[k] * sWcv[k * 64 + d]; }
            sRed[tid] = pm;
        }
        __syncthreads();
        if (tid < 64) {
            float v = 0.f;
            #pragma unroll
            for (int i = 0; i < 8; ++i) v += sRed[tid + 64 * i];
            sMv[tid] = v;
        }
        __syncthreads();
        #pragma unroll
        for (int ci = 0; ci < 2; ++ci) {
            int c = q * 2 + ci;
            float s = sBc[d] + ((c < ncol) ? sMv[d] : 0.f);
            for (int k = 0; k < 64; ++k) s += sChI[c * 64 + k] * sWc[k * 64 + d];
            float cn = tanhf(s);
            sChN[c * 64 + d] = cn;
            ch_out[(size_t)b * 1024 + c * 64 + d] = cn;   // identical across blocks of b
        }
        __syncthreads();
        {
            float pcs = 0.f;
            #pragma unroll
            for (int ci = 0; ci < 2; ++ci) { int c = q * 2 + ci; if (c < ncol) pcs += sChN[c * 64 + d]; }
            sRed[tid] = pcs;
        }
        __syncthreads();
        if (tid < 64) {
            float v = 0.f;
            #pragma unroll
            for (int i = 0; i < 8; ++i) v += sRed[tid + 64 * i];
            sCs[tid] = v;
        }
        __syncthreads();
    } else {
        {
            float pcs = 0.f;
            #pragma unroll
            for (int ci = 0; ci < 2; ++ci) { int c = q * 2 + ci; if (c < ncol) pcs += sChI[c * 64 + d]; }
            sRed[tid] = pcs;
        }
        __syncthreads();
        if (tid < 64) {
            float v = 0.f;
            #pragma unroll
            for (int i = 0; i < 8; ++i) v += sRed[tid + 64 * i];
            sCs[tid] = v;
        }
        __syncthreads();
    }
    {
        float pv = 0.f;
        #pragma unroll
        for (int j = 0; j < 8; ++j) { int k = q * 8 + j; pv += sCs[k] * sWvc[k * 64 + d]; }
        sRed[tid] = pv;
    }
    __syncthreads();
    if (tid < 64) {
        float v = sBv[tid];
        #pragma unroll
        for (int i = 0; i < 8; ++i) v += sRed[tid + 64 * i];
        sCv[tid] = v;
    }
    __syncthreads();

    // ---- phase 2: pre = vh@W_v + (v_agg + vh)@W_vv + cvec ; tanh ; writes ----
    int rt = (w & 3) * 16, ct = (w >> 2) * 32;   // wave: 16 rows x 32 cols

    f32x4 p2[2][2];   // [nt][kk]
    #pragma unroll
    for (int nt = 0; nt < 2; ++nt)
        #pragma unroll
        for (int kk = 0; kk < 2; ++kk) p2[nt][kk] = (f32x4){0.f, 0.f, 0.f, 0.f};

    #pragma unroll
    for (int kk = 0; kk < 2; ++kk) {
        int d0 = kk * 32 + lhi * 8;
        size_t vo = ((size_t)b * NN + m0 + rt + l16) * 64 + d0;
        bf16x8 a1h = *(const bf16x8*)(vhHi_in + vo);
        bf16x8 a1l = *(const bf16x8*)(vhLo_in + vo);
        int vb = (rt + l16) * 65 + d0;
        bf16x8 a2h, a2l;
        #pragma unroll
        for (int e = 0; e < 8; ++e) {
            float v = vagg[0][vb + e] + vagg[1][vb + e] + (float)a1h[e] + (float)a1l[e];
            bf16 h, l; split2(v, h, l);
            a2h[e] = h; a2l[e] = l;
        }
        #pragma unroll
        for (int nt = 0; nt < 2; ++nt) {
            int woff = (ct + nt * 16 + l16) * 64 + d0;
            bf16x8 b1h = *(const bf16x8*)(WvTh + woff);
            bf16x8 b1l = *(const bf16x8*)(WvTl + woff);
            bf16x8 b2h = *(const bf16x8*)(WvvTh + woff);
            bf16x8 b2l = *(const bf16x8*)(WvvTl + woff);
            p2[nt][kk] = __builtin_amdgcn_mfma_f32_16x16x32_bf16(a1h, b1h, p2[nt][kk], 0, 0, 0);
            p2[nt][kk] = __builtin_amdgcn_mfma_f32_16x16x32_bf16(a1l, b1h, p2[nt][kk], 0, 0, 0);
            p2[nt][kk] = __builtin_amdgcn_mfma_f32_16x16x32_bf16(a1h, b1l, p2[nt][kk], 0, 0, 0);
            p2[nt][kk] = __builtin_amdgcn_mfma_f32_16x16x32_bf16(a2h, b2h, p2[nt][kk], 0, 0, 0);
            p2[nt][kk] = __builtin_amdgcn_mfma_f32_16x16x32_bf16(a2l, b2h, p2[nt][kk], 0, 0, 0);
            p2[nt][kk] = __builtin_amdgcn_mfma_f32_16x16x32_bf16(a2h, b2l, p2[nt][kk], 0, 0, 0);
        }
    }

    int ksW = (m0 + rt) >> 5;
    int khi = 2 * ((rt >> 4) & 1) + (lhi >> 1);
    #pragma unroll
    for (int nt = 0; nt < 2; ++nt) {
        int col = ct + nt * 16 + l16;
        float cv = sCv[col];
        float tv[4];
        #pragma unroll
        for (int r = 0; r < 4; ++r) tv[r] = tanhf(p2[nt][0][r] + p2[nt][1][r] + cv);

        bf16x4 pkh, pkl;
        #pragma unroll
        for (int r = 0; r < 4; ++r) {
            bf16 h, l; split2(tv[r], h, l);
            size_t ro = ((size_t)b * NN + m0 + rt + lhi * 4 + r) * 64 + col;
            vhHi_out[ro] = h;
            vhLo_out[ro] = l;
            pkh[r] = h; pkl[r] = l;
        }
        size_t fo = (size_t)b * 65536 + (size_t)ksW * 2048 + col * 32 + khi * 8 + (lhi & 1) * 4;
        *(bf16x4*)(VfHi_out + fo) = pkh;
        *(bf16x4*)(VfLo_out + fo) = pkl;

        float cs = tv[0] + tv[1] + tv[2] + tv[3];
        cs += __shfl_xor(cs, 16);
        cs += __shfl_xor(cs, 32);
        if (lhi == 0)
            part_out[(((size_t)b * 16 + blkr) * 4 + (w & 3)) * 64 + col] = cs;
    }
}

// ---------------- final stage 1 ----------------
__global__ __launch_bounds__(256) void final_part_kernel(
    const bf16* __restrict__ vhHi, const bf16* __restrict__ vhLo,
    const float* __restrict__ W1, const float* __restrict__ b1,
    const float* __restrict__ W2, float* __restrict__ partial)
{
    __shared__ float sX[64 * 65];
    __shared__ float sW1[1024];
    __shared__ float sb1v[16], sW2v[16];
    __shared__ float sRed[256];
    int tid = threadIdx.x;
    int b = blockIdx.x & 15, blk = blockIdx.x >> 4, n0 = blk * 64;

    for (int e = tid; e < 1024; e += 256) sW1[e] = W1[e];
    if (tid < 16) { sb1v[tid] = b1[tid]; sW2v[tid] = W2[tid]; }
    {
        const bf16* gh = vhHi + ((size_t)b * NN + n0) * DD;
        const bf16* gl = vhLo + ((size_t)b * NN + n0) * DD;
        #pragma unroll
        for (int u = 0; u < 2; ++u) {
            int e = tid + u * 256;
            bf16x8 h8 = *(const bf16x8*)(gh + e * 8);
            bf16x8 l8 = *(const bf16x8*)(gl + e * 8);
            int row = e >> 3;
            int col = (e & 7) * 8;
            #pragma unroll
            for (int k = 0; k < 8; ++k) sX[row * 65 + col + k] = (float)h8[k] + (float)l8[k];
        }
    }
    __syncthreads();

    int nl = tid & 63, q = tid >> 6;
    float h[4];
    #pragma unroll
    for (int j = 0; j < 4; ++j) h[j] = sb1v[q * 4 + j];
    for (int dd = 0; dd < 64; ++dd) {
        float x = sX[nl * 65 + dd];
        #pragma unroll
        for (int j = 0; j < 4; ++j) h[j] += x * sW1[dd * 16 + q * 4 + j];
    }
    float pv = 0.f;
    #pragma unroll
    for (int j = 0; j < 4; ++j) pv += sW2v[q * 4 + j] / (1.f + expf(-h[j]));
    sRed[tid] = pv;
    __syncthreads();
    if (tid < 64) {
        float vote = sRed[tid] + sRed[tid + 64] + sRed[tid + 128] + sRed[tid + 192];
        #pragma unroll
        for (int off = 1; off < 64; off <<= 1) vote += __shfl_xor(vote, off);
        if (tid == 0) partial[blockIdx.x] = vote;
    }
}

// ---------------- final stage 2 ----------------
__global__ __launch_bounds__(256) void final_reduce_kernel(
    const float* __restrict__ partial, const float* __restrict__ b2, float* __restrict__ out)
{
    int tid = threadIdx.x;
    int b = tid >> 4, p = tid & 15;
    float v = partial[p * 16 + b];
    #pragma unroll
    for (int off = 1; off < 16; off <<= 1) v += __shfl_xor(v, off);
    if (p == 0) out[b] = 1.f / (1.f + expf(-(v / 1024.f + b2[0])));
}

extern "C" void kernel_launch(void* const* d_in, const int* in_sizes, int n_in,
                              void* d_out, int out_size, void* d_ws, size_t ws_size,
                              hipStream_t stream) {
    const float* Mvv  = (const float*)d_in[0];
    const int*   ncol = (const int*)d_in[1];
    const float* vini = (const float*)d_in[2];
    const float* ch0  = (const float*)d_in[3];
    const float* W_v  = (const float*)d_in[4];
    const float* W_vv = (const float*)d_in[5];
    const float* W_vc = (const float*)d_in[6];
    const float* b_v  = (const float*)d_in[7];
    const float* W_c  = (const float*)d_in[8];
    const float* W_cv = (const float*)d_in[9];
    const float* b_c  = (const float*)d_in[10];
    const float* W1   = (const float*)d_in[11];
    const float* b1   = (const float*)d_in[12];
    const float* W2   = (const float*)d_in[13];
    const float* b2   = (const float*)d_in[14];

    char* base = (char*)d_ws;
    size_t off = 0;
    u64* Abits = (u64*)(base + off); off += (size_t)BB * NN * 16 * 8;        // 2 MB
    const size_t SVH = (size_t)BB * NN * DD * 2;                              // 2 MB
    bf16* vhHi[2] = {(bf16*)(base + off), (bf16*)(base + off + SVH)}; off += 2 * SVH;
    bf16* vhLo[2] = {(bf16*)(base + off), (bf16*)(base + off + SVH)}; off += 2 * SVH;
    bf16* VfHi[2] = {(bf16*)(base + off), (bf16*)(base + off + SVH)}; off += 2 * SVH;
    bf16* VfLo[2] = {(bf16*)(base + off), (bf16*)(base + off + SVH)}; off += 2 * SVH;
    const size_t SCH = (size_t)BB * CC * DD * 4;
    float* chb[2] = {(float*)(base + off), (float*)(base + off + SCH)}; off += 2 * SCH;
    const size_t SPB = (size_t)BB * 64 * DD * 4;                              // 256 KB
    float* pb[2] = {(float*)(base + off), (float*)(base + off + SPB)}; off += 2 * SPB;
    bf16* WvTh  = (bf16*)(base + off); off += DD * DD * 2;
    bf16* WvTl  = (bf16*)(base + off); off += DD * DD * 2;
    bf16* WvvTh = (bf16*)(base + off); off += DD * DD * 2;
    bf16* WvvTl = (bf16*)(base + off); off += DD * DD * 2;
    float* partial = (float*)(base + off); off += 256 * 4;

    prep_kernel<<<5121, 256, 0, stream>>>(Mvv, vini, W_v, W_vv, Abits,
        vhHi[0], vhLo[0], VfHi[0], VfLo[0], WvTh, WvTl, WvvTh, WvvTl);

    for (int t = 0; t < TT; ++t) {
        const float* ch_in = (t <= 1) ? ch0 : chb[(t - 1) & 1];
        int i = t & 1, o = (t + 1) & 1;
        step_kernel<<<256, 512, 0, stream>>>(Abits,
            vhHi[i], vhLo[i], VfHi[i], VfLo[i],
            vhHi[o], vhLo[o], VfHi[o], VfLo[o],
            ch_in, chb[t & 1],
            pb[(t + 1) & 1], pb[t & 1],
            ncol, W_c, W_cv, b_c, W_vc, b_v,
            WvTh, WvTl, WvvTh, WvvTl, t);
    }

    final_part_kernel<<<256, 256, 0, stream>>>(vhHi[0], vhLo[0], W1, b1, W2, partial);
    final_reduce_kernel<<<1, 256, 0, stream>>>(partial, b2, (float*)d_out);
}